// Round 10
// baseline (332.433 us; speedup 1.0000x reference)
//
#include <hip/hip_runtime.h>
#include <hip/hip_bf16.h>

#define DM 1024
#define NH 16
#define DK 64
#define TT 2048
#define BATCH 2

typedef __attribute__((ext_vector_type(8))) short bf16x8;
typedef __attribute__((ext_vector_type(4))) float f32x4;
typedef __attribute__((ext_vector_type(4))) unsigned short u16x4;
typedef unsigned short u16;

__device__ inline u16 f2b(float x){ __hip_bfloat16 h = __float2bfloat16(x); return *reinterpret_cast<u16*>(&h); }

__device__ inline void gl_lds16(const u16* g, u16* l) {
  __builtin_amdgcn_global_load_lds(
      (const __attribute__((address_space(1))) unsigned int*)g,
      (__attribute__((address_space(3))) unsigned int*)l, 16, 0, 0);
}

// ---------- prep: fused fp32->bf16 activation convert (z<3) + weight transpose (z>=3) ----------
__global__ __launch_bounds__(256) void prep(const float* __restrict__ q, const float* __restrict__ k,
                                            const float* __restrict__ v,
                                            const float* __restrict__ wq, const float* __restrict__ wk,
                                            const float* __restrict__ wv, const float* __restrict__ wo,
                                            u16* __restrict__ qb, u16* __restrict__ kb,
                                            u16* __restrict__ vb, u16* __restrict__ wt) {
  int z = blockIdx.z;
  if (z < 3) {
    const float* src = z==0 ? q : z==1 ? k : v;
    u16* dst = z==0 ? qb : z==1 ? kb : vb;
    size_t i = ((size_t)blockIdx.x*256 + threadIdx.x)*8;
    f32x4 a = *(const f32x4*)(src+i);
    f32x4 b = *(const f32x4*)(src+i+4);
    union { bf16x8 v8; u16 e[8]; } u;
    #pragma unroll
    for (int j=0;j<4;j++){ u.e[j] = f2b(a[j]); u.e[4+j] = f2b(b[j]); }
    *(bf16x8*)(dst+i) = u.v8;
  } else {
    int bx = blockIdx.x;
    if (bx >= 1024) return;
    __shared__ float tile[32][33];
    const float* src = z==3 ? wq : z==4 ? wk : z==5 ? wv : wo;
    u16* dst = wt + (size_t)(z-3)*DM*DM;
    int bxx = bx & 31, byy = bx >> 5;
    int tx = threadIdx.x & 31, ty = threadIdx.x >> 5;   // 32 x 8
    int x  = bxx*32 + tx;
    int y0 = byy*32 + ty;
    #pragma unroll
    for (int i=0;i<32;i+=8) tile[ty+i][tx] = src[(size_t)(y0+i)*DM + x];
    __syncthreads();
    int xo = byy*32 + tx;
    int yo = bxx*32 + ty;
    #pragma unroll
    for (int i=0;i<32;i+=8) dst[(size_t)(yo+i)*DM + xo] = f2b(tile[tx][ty+i]);
  }
}

// ---------- QKV projection GEMM, v3: 256x256 tile, 8 waves, 8-phase schedule (T3+T4),
// ---------- counted vmcnt(4) twice/iter, granule-XOR LDS swizzle (T2), setprio (T5),
// ---------- XCD-chunked block swizzle (T1).
// mode 0 (z<2): row-major bf16 out [b*t][DM]; mode 1 (z==2): V-transposed [b,h,d,t] (u16x4).
// Q out is scaled by 0.125*log2(e) so flash can use exp2 (single v_exp_f32, no mul).
__global__ __launch_bounds__(512, 2) void gemm_qkv(const u16* __restrict__ qb, const u16* __restrict__ kb,
                                                   const u16* __restrict__ vb, const u16* __restrict__ wt,
                                                   const float* __restrict__ bq, const float* __restrict__ bk,
                                                   const float* __restrict__ bv,
                                                   u16* __restrict__ qh, u16* __restrict__ kh,
                                                   u16* __restrict__ vhT) {
  // flat grid 192 = 3z * 16m * 4n, XCD-chunked swizzle (192 % 8 == 0)
  const int bid = blockIdx.x;
  const int swz = (bid & 7)*24 + (bid >> 3);
  const int z  = swz >> 6;
  const int rb = swz & 63;
  const int row0 = (rb >> 2) * 256;
  const int col0 = (rb & 3) * 256;

  const u16* A = z==0 ? qb : z==1 ? kb : vb;
  const u16* W = wt + (size_t)z*DM*DM;
  const float* bias = z==0 ? bq : z==1 ? bk : bv;
  u16* outv = z==0 ? qh : z==1 ? kh : vhT;
  const int mode = (z==2);
  const float oscale = (z==0) ? 0.18033688f : 1.0f;   // 1/sqrt(64) * log2(e)

  // 2 slots x (A: 256x64 + B: 256x64) bf16 = 128 KiB
  __shared__ __align__(16) u16 As[2][16384];
  __shared__ __align__(16) u16 Bs[2][16384];

  const int tid = threadIdx.x, lane = tid & 63, wid = tid >> 6;
  const int li = lane & 15, quad = lane >> 4, l7 = lane & 7;
  const int wr = wid >> 2, wc = wid & 3;      // 2M x 4N waves, each owns 128x64 of C

  int r_[2], gs_[2];
  #pragma unroll
  for (int c=0;c<2;c++){ int idx = tid + c*512; int rr = idx>>3; int gd = idx&7; r_[c]=rr; gs_[c]=gd^(rr&7); }

  auto stage = [&](int op, int t, int hf, int slot){   // op: 0=A, 1=B(W)
    const u16* base = op ? W : A;
    const int rowbase = (op ? col0 : row0) + hf*128;
    u16* lb = (op ? Bs[slot] : As[slot]) + hf*8192;
    #pragma unroll
    for (int c=0;c<2;c++){
      gl_lds16(base + (size_t)(rowbase + r_[c])*DM + t*64 + gs_[c]*8,
               lb + ((wid*64 + c*512) << 3));
    }
  };

  f32x4 acc[8][4];
  #pragma unroll
  for (int i=0;i<8;i++)
    #pragma unroll
    for (int j=0;j<4;j++) acc[i][j] = f32x4{0.f,0.f,0.f,0.f};

  stage(1, 0, 0, 0); stage(1, 0, 1, 0);
  stage(0, 0, 0, 0); stage(0, 0, 1, 0);
  stage(1, 1, 0, 1); stage(1, 1, 1, 1);
  asm volatile("s_waitcnt vmcnt(4)" ::: "memory");
  __builtin_amdgcn_s_barrier();

  bf16x8 b[4][2];
  for (int i = 0; i < 8; i++) {
    const int t2 = 2*i;
    #pragma unroll
    for (int half = 0; half < 2; half++) {
      const int slot = half;
      #pragma unroll
      for (int q = 0; q < 4; q++) {
        if (q == 0) {
          const u16* bb = Bs[slot] + (wc>>1)*8192 + (wc&1)*4096;
          #pragma unroll
          for (int c=0;c<4;c++)
            #pragma unroll
            for (int kh=0;kh<2;kh++)
              b[c][kh] = *(const bf16x8*)&bb[(c*16 + li)*64 + ((quad + 4*kh) ^ l7)*8];
        }
        bf16x8 a[2][2];
        {
          const u16* ab = As[slot] + wr*8192;
          #pragma unroll
          for (int rr2=0; rr2<2; rr2++)
            #pragma unroll
            for (int kh=0;kh<2;kh++)
              a[rr2][kh] = *(const bf16x8*)&ab[((q*2+rr2)*16 + li)*64 + ((quad + 4*kh) ^ l7)*8];
        }
        {
          const int sop = (q >= 2);
          const int st  = t2 + 1 + half + (q >= 2);
          const int shf = q & 1;
          const int ssl = (q >= 2) ? half : (1 - half);
          if (st <= 15) stage(sop, st, shf, ssl);
        }
        if (q == 0) asm volatile("s_waitcnt lgkmcnt(8)" ::: "memory");
        __builtin_amdgcn_s_barrier();
        asm volatile("s_waitcnt lgkmcnt(0)" ::: "memory");
        __builtin_amdgcn_sched_barrier(0);
        __builtin_amdgcn_s_setprio(1);
        #pragma unroll
        for (int rr2=0; rr2<2; rr2++)
          #pragma unroll
          for (int c=0;c<4;c++)
            #pragma unroll
            for (int kh=0;kh<2;kh++)
              acc[q*2+rr2][c] = __builtin_amdgcn_mfma_f32_16x16x32_bf16(a[rr2][kh], b[c][kh], acc[q*2+rr2][c], 0,0,0);
        __builtin_amdgcn_s_setprio(0);
        if (q == 3) {
          if (half == 0) {
            if (i < 7) asm volatile("s_waitcnt vmcnt(4)" ::: "memory");
            else       asm volatile("s_waitcnt vmcnt(0)" ::: "memory");
          } else {
            if (i < 7) asm volatile("s_waitcnt vmcnt(4)" ::: "memory");
          }
        }
        __builtin_amdgcn_s_barrier();
      }
    }
  }

  // C layout: col=lane&15, row=quad*4+reg  [m89/m91]
  if (!mode) {
    #pragma unroll
    for (int c=0;c<4;c++) {
      int col = col0 + wc*64 + c*16 + li;
      float bsv = bias[col];
      #pragma unroll
      for (int fr=0; fr<8; fr++) {
        int rowb = row0 + wr*128 + fr*16 + quad*4;
        #pragma unroll
        for (int r=0;r<4;r++)
          outv[(size_t)(rowb + r)*DM + col] = f2b((acc[fr][c][r] + bsv) * oscale);
      }
    }
  } else {
    #pragma unroll
    for (int c=0;c<4;c++) {
      int col = col0 + wc*64 + c*16 + li;
      float bsv = bias[col];
      int hh = col >> 6, d = col & 63;
      #pragma unroll
      for (int fr=0; fr<8; fr++) {
        int rowb = row0 + wr*128 + fr*16 + quad*4;
        int bb = rowb >> 11, t0 = rowb & (TT-1);
        u16x4 w;
        #pragma unroll
        for (int r=0;r<4;r++) w[r] = f2b(acc[fr][c][r] + bsv);
        *(u16x4*)&outv[(((size_t)(bb*NH + hh)*DK + d)*TT) + t0] = w;
      }
    }
  }
}

// ---------- output GEMM, v2: depth-2 pipeline + swizzle, 128x64 tiles ----------
__global__ __launch_bounds__(256) void gemm_out64(const u16* __restrict__ A, const u16* __restrict__ W,
                                                  const float* __restrict__ bias, float* __restrict__ out) {
  __shared__ __align__(16) u16 As[3][128*32];
  __shared__ __align__(16) u16 Bs[3][64*32];
  const int tid = threadIdx.x, lane = tid & 63, wid = tid >> 6;
  const int li = lane & 15, quad = lane >> 4;
  const int row0 = blockIdx.x*128, col0 = blockIdx.y*64;
  const int wr = wid & 1, wc = wid >> 1;

  const int srow = lane >> 2;
  const int scol = ((lane & 3) ^ ((srow >> 1) & 3)) * 8;
  const int rsw  = (li >> 1) & 3;

  auto stage = [&](int hh, int bufi) {
    const int kk = hh*32;
    #pragma unroll
    for (int c=0;c<2;c++) {
      int ch = wid*2 + c;
      gl_lds16(A + (size_t)(row0 + ch*16 + srow)*DM + kk + scol, &As[bufi][ch*512]);
    }
    gl_lds16(W + (size_t)(col0 + wid*16 + srow)*DM + kk + scol, &Bs[bufi][wid*512]);
  };

  f32x4 acc[4][2];
  #pragma unroll
  for (int i=0;i<4;i++)
    #pragma unroll
    for (int j=0;j<2;j++) acc[i][j] = f32x4{0.f,0.f,0.f,0.f};

  stage(0, 0);
  stage(1, 1);
  asm volatile("s_waitcnt vmcnt(3)" ::: "memory");
  __builtin_amdgcn_s_barrier();

  int buf = 0;
  for (int h = 0; h < 32; h++) {
    bf16x8 a[4], b[2];
    #pragma unroll
    for (int i=0;i<4;i++) a[i] = *(const bf16x8*)&As[buf][(wr*64 + i*16 + li)*32 + (quad ^ rsw)*8];
    #pragma unroll
    for (int j=0;j<2;j++) b[j] = *(const bf16x8*)&Bs[buf][(wc*32 + j*16 + li)*32 + (quad ^ rsw)*8];

    if (h < 30) { int nb = buf + 2; if (nb >= 3) nb -= 3; stage(h+2, nb); }

    __builtin_amdgcn_s_setprio(1);
    #pragma unroll
    for (int i=0;i<4;i++)
      #pragma unroll
      for (int j=0;j<2;j++)
        acc[i][j] = __builtin_amdgcn_mfma_f32_16x16x32_bf16(a[i], b[j], acc[i][j], 0,0,0);
    __builtin_amdgcn_s_setprio(0);

    if (h < 30)       asm volatile("s_waitcnt vmcnt(3)" ::: "memory");
    else if (h == 30) asm volatile("s_waitcnt vmcnt(0)" ::: "memory");
    __builtin_amdgcn_s_barrier();
    if (++buf == 3) buf = 0;
  }

  #pragma unroll
  for (int j=0;j<2;j++) {
    int col = col0 + wc*32 + j*16 + li;
    float bsv = bias[col];
    #pragma unroll
    for (int i=0;i<4;i++) {
      #pragma unroll
      for (int r=0;r<4;r++) {
        int row = row0 + wr*64 + i*16 + quad*4 + r;
        out[(size_t)row*DM + col] = acc[i][j][r] + bsv;
      }
    }
  }
}

// ---------- flash v10: NO K/V LDS staging, NO __syncthreads. K/V (16 MB total) is
// ---------- L2/L3-resident; kf/vf fragments read directly from global (4 waves of a
// ---------- block walk the same 16 KB chunk -> L1 reuse). Every wave fully independent:
// ---------- no barrier phase-locking (r8 lesson), waves de-phase and overlap pipes.
// ---------- Occupancy: launch_bounds(256,4) -> VGPR cap 128 (demand ~105), LDS 16 KiB
// ---------- (Pb only) -> 4 blocks/CU = 16 waves/CU (was 8, barrier-coupled).
// ---------- Wave exits its k-loop at the diagonal (wave-uniform break, no barriers).
__global__ __launch_bounds__(256, 4) void flash(const u16* __restrict__ qh, const u16* __restrict__ kh,
                                                const u16* __restrict__ vhT, u16* __restrict__ ctx) {
  const int bh = blockIdx.x;                   // 0..31
  const int y  = blockIdx.y;                   // 0..15
  const int qt = (y < 8) ? (15 - y) : (y - 8); // complementary totals pairing
  const int b = bh >> 4, h = bh & 15;
  const u16* Q  = qh  + (size_t)b*TT*DM + h*DK;
  const u16* K  = kh  + (size_t)b*TT*DM + h*DK;
  const u16* Vt = vhT + (size_t)bh*DK*TT;      // [d][t]

  const int tid = threadIdx.x, lane = tid & 63, wid = tid >> 6;
  const int li = lane & 15, quad = lane >> 4, l7 = lane & 7;

  __shared__ __align__(16) u16 Pb[4][16][64];  // per-wave P transpose buffer (only LDS)

  const int qw0 = qt*128 + wid*32;             // wave q base (32 q per wave)
  const int ntw = (qw0 + 31)/64 + 1;           // live 64-key chunks for this wave

  bf16x8 qf[2][2];
  #pragma unroll
  for (int su=0; su<2; su++)
    #pragma unroll
    for (int k2=0; k2<2; k2++)
      qf[su][k2] = *(const bf16x8*)&Q[(size_t)(qw0 + su*16 + li)*DM + k2*32 + quad*8];

  f32x4 o[2][4];
  #pragma unroll
  for (int su=0; su<2; su++)
    #pragma unroll
    for (int d=0; d<4; d++) o[su][d] = f32x4{0.f,0.f,0.f,0.f};
  float lp[2] = {0.f, 0.f};

  for (int n = 0; n < ntw; n++) {
    const int k0 = n*64;

    // ---- QK: S^T = K @ Q^T, kf direct from global (L1/L2) ----
    f32x4 sacc[2][4];
    #pragma unroll
    for (int c=0;c<4;c++) {
      const u16* krow = &K[(size_t)(k0 + c*16 + li)*DM];
      bf16x8 kf0 = *(const bf16x8*)&krow[     quad*8];
      bf16x8 kf1 = *(const bf16x8*)&krow[32 + quad*8];
      #pragma unroll
      for (int su=0; su<2; su++) {
        f32x4 t = __builtin_amdgcn_mfma_f32_16x16x32_bf16(kf0, qf[su][0], f32x4{0.f,0.f,0.f,0.f}, 0,0,0);
        sacc[su][c] = __builtin_amdgcn_mfma_f32_16x16x32_bf16(kf1, qf[su][1], t, 0,0,0);
      }
    }

    // ---- vf direct from global (shared by both su) ----
    bf16x8 vf[4][2];
    #pragma unroll
    for (int d=0; d<4; d++) {
      const u16* vrow = &Vt[(size_t)(d*16 + li)*TT + k0];
      vf[d][0] = *(const bf16x8*)&vrow[     quad*8];
      vf[d][1] = *(const bf16x8*)&vrow[32 + quad*8];
    }

    const bool dg = (k0 + 63 > qw0);           // masking possible this chunk
    #pragma unroll
    for (int su=0; su<2; su++) {
      const int qr = qw0 + su*16;
      if (k0 <= qr + 15) {                     // subtile not entirely above diagonal
        const int qq = qr + li;
        float p[4][4];
        if (dg) {
          #pragma unroll
          for (int c=0;c<4;c++)
            #pragma unroll
            for (int r=0;r<4;r++){
              int key = k0 + c*16 + quad*4 + r;
              p[c][r] = (key <= qq) ? exp2f(sacc[su][c][r]) : 0.f;
            }
        } else {
          #pragma unroll
          for (int c=0;c<4;c++)
            #pragma unroll
            for (int r=0;r<4;r++)
              p[c][r] = exp2f(sacc[su][c][r]);
        }
        #pragma unroll
        for (int c=0;c<4;c++)
          #pragma unroll
          for (int r=0;r<4;r++)
            lp[su] += p[c][r];

        // P -> Pb (swizzled) -> pf fragments (wave-local; wave_barrier only)
        #pragma unroll
        for (int c=0;c<4;c++) {
          u16x4 wv;
          #pragma unroll
          for (int r=0;r<4;r++) wv[r] = f2b(p[c][r]);
          const int gc = c*2 + (quad>>1);
          *(u16x4*)&Pb[wid][li][((gc ^ l7)*8) + (quad&1)*4] = wv;
        }
        __builtin_amdgcn_wave_barrier();
        __asm__ __volatile__("s_waitcnt lgkmcnt(0)");
        bf16x8 pf0 = *(const bf16x8*)&Pb[wid][li][((quad    ) ^ l7)*8];
        bf16x8 pf1 = *(const bf16x8*)&Pb[wid][li][((quad + 4) ^ l7)*8];
        __asm__ __volatile__("s_waitcnt lgkmcnt(0)");     // reads done before su=1 rewrites Pb

        #pragma unroll
        for (int d=0;d<4;d++){
          o[su][d] = __builtin_amdgcn_mfma_f32_16x16x32_bf16(vf[d][0], pf0, o[su][d], 0,0,0);
          o[su][d] = __builtin_amdgcn_mfma_f32_16x16x32_bf16(vf[d][1], pf1, o[su][d], 0,0,0);
        }
      }
    }
  }

  #pragma unroll
  for (int su=0; su<2; su++) {
    float lpv = lp[su];
    lpv += __shfl_xor(lpv, 16, 64);
    lpv += __shfl_xor(lpv, 32, 64);
    float rl = 1.0f / lpv;
    const int qq = qw0 + su*16 + li;
    #pragma unroll
    for (int d=0;d<4;d++){
      u16x4 wv;
      #pragma unroll
      for (int r=0;r<4;r++) wv[r] = f2b(o[su][d][r] * rl);
      *(u16x4*)&ctx[(size_t)(b*TT + qq)*DM + h*DK + d*16 + quad*4] = wv;
    }
  }
}

extern "C" void kernel_launch(void* const* d_in, const int* in_sizes, int n_in,
                              void* d_out, int out_size, void* d_ws, size_t ws_size,
                              hipStream_t stream) {
  const float* q   = (const float*)d_in[0];
  const float* k   = (const float*)d_in[1];
  const float* v   = (const float*)d_in[2];
  // d_in[3]: mask (int32 causal tril) — causality hard-coded in flash kernel
  const float* wq  = (const float*)d_in[4];
  const float* bq  = (const float*)d_in[5];
  const float* wk  = (const float*)d_in[6];
  const float* bk  = (const float*)d_in[7];
  const float* wv  = (const float*)d_in[8];
  const float* bv  = (const float*)d_in[9];
  const float* wo  = (const float*)d_in[10];
  const float* bo  = (const float*)d_in[11];
  float* out = (float*)d_out;

  const size_t SZ = (size_t)BATCH*TT*DM;
  u16* wt  = (u16*)d_ws;                        // 4 x 1024x1024 bf16 = 8 MB
  u16* qb  = wt + (size_t)4*DM*DM;
  u16* kb  = qb + SZ;
  u16* vb  = kb + SZ;
  u16* qh  = vb + SZ;
  u16* kh  = qh + SZ;
  u16* vhT = kh + SZ;
  u16* ctx = qb;                                // alias: qb dead after gemm_qkv

  prep<<<dim3(2048, 1, 7), 256, 0, stream>>>(q, k, v, wq, wk, wv, wo, qb, kb, vb, wt);

  gemm_qkv<<<dim3(192, 1, 1), 512, 0, stream>>>(qb, kb, vb, wt, bq, bk, bv, qh, kh, vhT);

  flash<<<dim3(BATCH*NH, 16), 256, 0, stream>>>(qh, kh, vhT, ctx);

  gemm_out64<<<dim3(4096/128, DM/64), 256, 0, stream>>>(ctx, wt + (size_t)3*DM*DM, bo, out);
}

// Round 11
// 246.158 us; speedup vs baseline: 1.3505x; 1.3505x over previous
//
#include <hip/hip_runtime.h>
#include <hip/hip_bf16.h>

#define DM 1024
#define NH 16
#define DK 64
#define TT 2048
#define BATCH 2

typedef __attribute__((ext_vector_type(8))) short bf16x8;
typedef __attribute__((ext_vector_type(4))) float f32x4;
typedef __attribute__((ext_vector_type(4))) unsigned short u16x4;
typedef unsigned short u16;

__device__ inline u16 f2b(float x){ __hip_bfloat16 h = __float2bfloat16(x); return *reinterpret_cast<u16*>(&h); }

__device__ inline void gl_lds16(const u16* g, u16* l) {
  __builtin_amdgcn_global_load_lds(
      (const __attribute__((address_space(1))) unsigned int*)g,
      (__attribute__((address_space(3))) unsigned int*)l, 16, 0, 0);
}

// ---------- prep: fused fp32->bf16 activation convert (z<3) + weight transpose (z>=3) ----------
__global__ __launch_bounds__(256) void prep(const float* __restrict__ q, const float* __restrict__ k,
                                            const float* __restrict__ v,
                                            const float* __restrict__ wq, const float* __restrict__ wk,
                                            const float* __restrict__ wv, const float* __restrict__ wo,
                                            u16* __restrict__ qb, u16* __restrict__ kb,
                                            u16* __restrict__ vb, u16* __restrict__ wt) {
  int z = blockIdx.z;
  if (z < 3) {
    const float* src = z==0 ? q : z==1 ? k : v;
    u16* dst = z==0 ? qb : z==1 ? kb : vb;
    size_t i = ((size_t)blockIdx.x*256 + threadIdx.x)*8;
    f32x4 a = *(const f32x4*)(src+i);
    f32x4 b = *(const f32x4*)(src+i+4);
    union { bf16x8 v8; u16 e[8]; } u;
    #pragma unroll
    for (int j=0;j<4;j++){ u.e[j] = f2b(a[j]); u.e[4+j] = f2b(b[j]); }
    *(bf16x8*)(dst+i) = u.v8;
  } else {
    int bx = blockIdx.x;
    if (bx >= 1024) return;
    __shared__ float tile[32][33];
    const float* src = z==3 ? wq : z==4 ? wk : z==5 ? wv : wo;
    u16* dst = wt + (size_t)(z-3)*DM*DM;
    int bxx = bx & 31, byy = bx >> 5;
    int tx = threadIdx.x & 31, ty = threadIdx.x >> 5;   // 32 x 8
    int x  = bxx*32 + tx;
    int y0 = byy*32 + ty;
    #pragma unroll
    for (int i=0;i<32;i+=8) tile[ty+i][tx] = src[(size_t)(y0+i)*DM + x];
    __syncthreads();
    int xo = byy*32 + tx;
    int yo = bxx*32 + ty;
    #pragma unroll
    for (int i=0;i<32;i+=8) dst[(size_t)(yo+i)*DM + xo] = f2b(tile[tx][ty+i]);
  }
}

// ---------- QKV projection GEMM, v3: 256x256 tile, 8 waves, 8-phase schedule (T3+T4),
// ---------- counted vmcnt(4) twice/iter, granule-XOR LDS swizzle (T2), setprio (T5),
// ---------- XCD-chunked block swizzle (T1).
// mode 0 (z<2): row-major bf16 out [b*t][DM]; mode 1 (z==2): V-transposed [b,h,d,t] (u16x4).
// Q out is scaled by 0.125*log2(e) so flash can use exp2 (single v_exp_f32, no mul).
__global__ __launch_bounds__(512, 2) void gemm_qkv(const u16* __restrict__ qb, const u16* __restrict__ kb,
                                                   const u16* __restrict__ vb, const u16* __restrict__ wt,
                                                   const float* __restrict__ bq, const float* __restrict__ bk,
                                                   const float* __restrict__ bv,
                                                   u16* __restrict__ qh, u16* __restrict__ kh,
                                                   u16* __restrict__ vhT) {
  // flat grid 192 = 3z * 16m * 4n, XCD-chunked swizzle (192 % 8 == 0)
  const int bid = blockIdx.x;
  const int swz = (bid & 7)*24 + (bid >> 3);
  const int z  = swz >> 6;
  const int rb = swz & 63;
  const int row0 = (rb >> 2) * 256;
  const int col0 = (rb & 3) * 256;

  const u16* A = z==0 ? qb : z==1 ? kb : vb;
  const u16* W = wt + (size_t)z*DM*DM;
  const float* bias = z==0 ? bq : z==1 ? bk : bv;
  u16* outv = z==0 ? qh : z==1 ? kh : vhT;
  const int mode = (z==2);
  const float oscale = (z==0) ? 0.18033688f : 1.0f;   // 1/sqrt(64) * log2(e)

  // 2 slots x (A: 256x64 + B: 256x64) bf16 = 128 KiB
  __shared__ __align__(16) u16 As[2][16384];
  __shared__ __align__(16) u16 Bs[2][16384];

  const int tid = threadIdx.x, lane = tid & 63, wid = tid >> 6;
  const int li = lane & 15, quad = lane >> 4, l7 = lane & 7;
  const int wr = wid >> 2, wc = wid & 3;      // 2M x 4N waves, each owns 128x64 of C

  int r_[2], gs_[2];
  #pragma unroll
  for (int c=0;c<2;c++){ int idx = tid + c*512; int rr = idx>>3; int gd = idx&7; r_[c]=rr; gs_[c]=gd^(rr&7); }

  auto stage = [&](int op, int t, int hf, int slot){   // op: 0=A, 1=B(W)
    const u16* base = op ? W : A;
    const int rowbase = (op ? col0 : row0) + hf*128;
    u16* lb = (op ? Bs[slot] : As[slot]) + hf*8192;
    #pragma unroll
    for (int c=0;c<2;c++){
      gl_lds16(base + (size_t)(rowbase + r_[c])*DM + t*64 + gs_[c]*8,
               lb + ((wid*64 + c*512) << 3));
    }
  };

  f32x4 acc[8][4];
  #pragma unroll
  for (int i=0;i<8;i++)
    #pragma unroll
    for (int j=0;j<4;j++) acc[i][j] = f32x4{0.f,0.f,0.f,0.f};

  stage(1, 0, 0, 0); stage(1, 0, 1, 0);
  stage(0, 0, 0, 0); stage(0, 0, 1, 0);
  stage(1, 1, 0, 1); stage(1, 1, 1, 1);
  asm volatile("s_waitcnt vmcnt(4)" ::: "memory");
  __builtin_amdgcn_s_barrier();

  bf16x8 b[4][2];
  for (int i = 0; i < 8; i++) {
    const int t2 = 2*i;
    #pragma unroll
    for (int half = 0; half < 2; half++) {
      const int slot = half;
      #pragma unroll
      for (int q = 0; q < 4; q++) {
        if (q == 0) {
          const u16* bb = Bs[slot] + (wc>>1)*8192 + (wc&1)*4096;
          #pragma unroll
          for (int c=0;c<4;c++)
            #pragma unroll
            for (int kh=0;kh<2;kh++)
              b[c][kh] = *(const bf16x8*)&bb[(c*16 + li)*64 + ((quad + 4*kh) ^ l7)*8];
        }
        bf16x8 a[2][2];
        {
          const u16* ab = As[slot] + wr*8192;
          #pragma unroll
          for (int rr2=0; rr2<2; rr2++)
            #pragma unroll
            for (int kh=0;kh<2;kh++)
              a[rr2][kh] = *(const bf16x8*)&ab[((q*2+rr2)*16 + li)*64 + ((quad + 4*kh) ^ l7)*8];
        }
        {
          const int sop = (q >= 2);
          const int st  = t2 + 1 + half + (q >= 2);
          const int shf = q & 1;
          const int ssl = (q >= 2) ? half : (1 - half);
          if (st <= 15) stage(sop, st, shf, ssl);
        }
        if (q == 0) asm volatile("s_waitcnt lgkmcnt(8)" ::: "memory");
        __builtin_amdgcn_s_barrier();
        asm volatile("s_waitcnt lgkmcnt(0)" ::: "memory");
        __builtin_amdgcn_sched_barrier(0);
        __builtin_amdgcn_s_setprio(1);
        #pragma unroll
        for (int rr2=0; rr2<2; rr2++)
          #pragma unroll
          for (int c=0;c<4;c++)
            #pragma unroll
            for (int kh=0;kh<2;kh++)
              acc[q*2+rr2][c] = __builtin_amdgcn_mfma_f32_16x16x32_bf16(a[rr2][kh], b[c][kh], acc[q*2+rr2][c], 0,0,0);
        __builtin_amdgcn_s_setprio(0);
        if (q == 3) {
          if (half == 0) {
            if (i < 7) asm volatile("s_waitcnt vmcnt(4)" ::: "memory");
            else       asm volatile("s_waitcnt vmcnt(0)" ::: "memory");
          } else {
            if (i < 7) asm volatile("s_waitcnt vmcnt(4)" ::: "memory");
          }
        }
        __builtin_amdgcn_s_barrier();
      }
    }
  }

  // C layout: col=lane&15, row=quad*4+reg  [m89/m91]
  if (!mode) {
    #pragma unroll
    for (int c=0;c<4;c++) {
      int col = col0 + wc*64 + c*16 + li;
      float bsv = bias[col];
      #pragma unroll
      for (int fr=0; fr<8; fr++) {
        int rowb = row0 + wr*128 + fr*16 + quad*4;
        #pragma unroll
        for (int r=0;r<4;r++)
          outv[(size_t)(rowb + r)*DM + col] = f2b((acc[fr][c][r] + bsv) * oscale);
      }
    }
  } else {
    #pragma unroll
    for (int c=0;c<4;c++) {
      int col = col0 + wc*64 + c*16 + li;
      float bsv = bias[col];
      int hh = col >> 6, d = col & 63;
      #pragma unroll
      for (int fr=0; fr<8; fr++) {
        int rowb = row0 + wr*128 + fr*16 + quad*4;
        int bb = rowb >> 11, t0 = rowb & (TT-1);
        u16x4 w;
        #pragma unroll
        for (int r=0;r<4;r++) w[r] = f2b(acc[fr][c][r] + bsv);
        *(u16x4*)&outv[(((size_t)(bb*NH + hh)*DK + d)*TT) + t0] = w;
      }
    }
  }
}

// ---------- output GEMM, v2: depth-2 pipeline + swizzle, 128x64 tiles ----------
__global__ __launch_bounds__(256) void gemm_out64(const u16* __restrict__ A, const u16* __restrict__ W,
                                                  const float* __restrict__ bias, float* __restrict__ out) {
  __shared__ __align__(16) u16 As[3][128*32];
  __shared__ __align__(16) u16 Bs[3][64*32];
  const int tid = threadIdx.x, lane = tid & 63, wid = tid >> 6;
  const int li = lane & 15, quad = lane >> 4;
  const int row0 = blockIdx.x*128, col0 = blockIdx.y*64;
  const int wr = wid & 1, wc = wid >> 1;

  const int srow = lane >> 2;
  const int scol = ((lane & 3) ^ ((srow >> 1) & 3)) * 8;
  const int rsw  = (li >> 1) & 3;

  auto stage = [&](int hh, int bufi) {
    const int kk = hh*32;
    #pragma unroll
    for (int c=0;c<2;c++) {
      int ch = wid*2 + c;
      gl_lds16(A + (size_t)(row0 + ch*16 + srow)*DM + kk + scol, &As[bufi][ch*512]);
    }
    gl_lds16(W + (size_t)(col0 + wid*16 + srow)*DM + kk + scol, &Bs[bufi][wid*512]);
  };

  f32x4 acc[4][2];
  #pragma unroll
  for (int i=0;i<4;i++)
    #pragma unroll
    for (int j=0;j<2;j++) acc[i][j] = f32x4{0.f,0.f,0.f,0.f};

  stage(0, 0);
  stage(1, 1);
  asm volatile("s_waitcnt vmcnt(3)" ::: "memory");
  __builtin_amdgcn_s_barrier();

  int buf = 0;
  for (int h = 0; h < 32; h++) {
    bf16x8 a[4], b[2];
    #pragma unroll
    for (int i=0;i<4;i++) a[i] = *(const bf16x8*)&As[buf][(wr*64 + i*16 + li)*32 + (quad ^ rsw)*8];
    #pragma unroll
    for (int j=0;j<2;j++) b[j] = *(const bf16x8*)&Bs[buf][(wc*32 + j*16 + li)*32 + (quad ^ rsw)*8];

    if (h < 30) { int nb = buf + 2; if (nb >= 3) nb -= 3; stage(h+2, nb); }

    __builtin_amdgcn_s_setprio(1);
    #pragma unroll
    for (int i=0;i<4;i++)
      #pragma unroll
      for (int j=0;j<2;j++)
        acc[i][j] = __builtin_amdgcn_mfma_f32_16x16x32_bf16(a[i], b[j], acc[i][j], 0,0,0);
    __builtin_amdgcn_s_setprio(0);

    if (h < 30)       asm volatile("s_waitcnt vmcnt(3)" ::: "memory");
    else if (h == 30) asm volatile("s_waitcnt vmcnt(0)" ::: "memory");
    __builtin_amdgcn_s_barrier();
    if (++buf == 3) buf = 0;
  }

  #pragma unroll
  for (int j=0;j<2;j++) {
    int col = col0 + wc*32 + j*16 + li;
    float bsv = bias[col];
    #pragma unroll
    for (int i=0;i<4;i++) {
      #pragma unroll
      for (int r=0;r<4;r++) {
        int row = row0 + wr*64 + i*16 + quad*4 + r;
        out[(size_t)row*DM + col] = acc[i][j][r] + bsv;
      }
    }
  }
}

// ---------- flash v11: v10 structure (no K/V LDS, no __syncthreads, independent waves,
// ---------- K/V L2/L3-resident direct-global reads — r10 counters confirmed ~zero extra
// ---------- HBM fetch) with the register cap FIXED: plain __launch_bounds__(256).
// ---------- Empirical rule this session: 2nd launch_bounds arg w caps VGPR at 256/w
// ---------- (w=4 -> 64, spilled twice: r7 345MB, r10 40MB scratch). No 2nd arg ->
// ---------- compiler picks ~100 VGPR (v7/v9 measured), no spill; LDS 8 KiB -> occupancy
// ---------- VGPR-limited at ~16 waves/CU of de-phased independent waves.
__global__ __launch_bounds__(256) void flash(const u16* __restrict__ qh, const u16* __restrict__ kh,
                                             const u16* __restrict__ vhT, u16* __restrict__ ctx) {
  const int bh = blockIdx.x;                   // 0..31
  const int y  = blockIdx.y;                   // 0..15
  const int qt = (y < 8) ? (15 - y) : (y - 8); // complementary totals pairing
  const int b = bh >> 4, h = bh & 15;
  const u16* Q  = qh  + (size_t)b*TT*DM + h*DK;
  const u16* K  = kh  + (size_t)b*TT*DM + h*DK;
  const u16* Vt = vhT + (size_t)bh*DK*TT;      // [d][t]

  const int tid = threadIdx.x, lane = tid & 63, wid = tid >> 6;
  const int li = lane & 15, quad = lane >> 4, l7 = lane & 7;

  __shared__ __align__(16) u16 Pb[4][16][64];  // per-wave P transpose buffer (only LDS)

  const int qw0 = qt*128 + wid*32;             // wave q base (32 q per wave)
  const int ntw = (qw0 + 31)/64 + 1;           // live 64-key chunks for this wave

  bf16x8 qf[2][2];
  #pragma unroll
  for (int su=0; su<2; su++)
    #pragma unroll
    for (int k2=0; k2<2; k2++)
      qf[su][k2] = *(const bf16x8*)&Q[(size_t)(qw0 + su*16 + li)*DM + k2*32 + quad*8];

  f32x4 o[2][4];
  #pragma unroll
  for (int su=0; su<2; su++)
    #pragma unroll
    for (int d=0; d<4; d++) o[su][d] = f32x4{0.f,0.f,0.f,0.f};
  float lp[2] = {0.f, 0.f};

  for (int n = 0; n < ntw; n++) {
    const int k0 = n*64;

    // ---- QK: S^T = K @ Q^T, kf direct from global (L1/L2) ----
    f32x4 sacc[2][4];
    #pragma unroll
    for (int c=0;c<4;c++) {
      const u16* krow = &K[(size_t)(k0 + c*16 + li)*DM];
      bf16x8 kf0 = *(const bf16x8*)&krow[     quad*8];
      bf16x8 kf1 = *(const bf16x8*)&krow[32 + quad*8];
      #pragma unroll
      for (int su=0; su<2; su++) {
        f32x4 t = __builtin_amdgcn_mfma_f32_16x16x32_bf16(kf0, qf[su][0], f32x4{0.f,0.f,0.f,0.f}, 0,0,0);
        sacc[su][c] = __builtin_amdgcn_mfma_f32_16x16x32_bf16(kf1, qf[su][1], t, 0,0,0);
      }
    }

    // ---- vf direct from global (shared by both su) ----
    bf16x8 vf[4][2];
    #pragma unroll
    for (int d=0; d<4; d++) {
      const u16* vrow = &Vt[(size_t)(d*16 + li)*TT + k0];
      vf[d][0] = *(const bf16x8*)&vrow[     quad*8];
      vf[d][1] = *(const bf16x8*)&vrow[32 + quad*8];
    }

    const bool dg = (k0 + 63 > qw0);           // masking possible this chunk
    #pragma unroll
    for (int su=0; su<2; su++) {
      const int qr = qw0 + su*16;
      if (k0 <= qr + 15) {                     // subtile not entirely above diagonal
        const int qq = qr + li;
        float p[4][4];
        if (dg) {
          #pragma unroll
          for (int c=0;c<4;c++)
            #pragma unroll
            for (int r=0;r<4;r++){
              int key = k0 + c*16 + quad*4 + r;
              p[c][r] = (key <= qq) ? exp2f(sacc[su][c][r]) : 0.f;
            }
        } else {
          #pragma unroll
          for (int c=0;c<4;c++)
            #pragma unroll
            for (int r=0;r<4;r++)
              p[c][r] = exp2f(sacc[su][c][r]);
        }
        #pragma unroll
        for (int c=0;c<4;c++)
          #pragma unroll
          for (int r=0;r<4;r++)
            lp[su] += p[c][r];

        // P -> Pb (swizzled) -> pf fragments (wave-local; wave_barrier only)
        #pragma unroll
        for (int c=0;c<4;c++) {
          u16x4 wv;
          #pragma unroll
          for (int r=0;r<4;r++) wv[r] = f2b(p[c][r]);
          const int gc = c*2 + (quad>>1);
          *(u16x4*)&Pb[wid][li][((gc ^ l7)*8) + (quad&1)*4] = wv;
        }
        __builtin_amdgcn_wave_barrier();
        __asm__ __volatile__("s_waitcnt lgkmcnt(0)");
        bf16x8 pf0 = *(const bf16x8*)&Pb[wid][li][((quad    ) ^ l7)*8];
        bf16x8 pf1 = *(const bf16x8*)&Pb[wid][li][((quad + 4) ^ l7)*8];
        __asm__ __volatile__("s_waitcnt lgkmcnt(0)");     // reads done before su=1 rewrites Pb

        #pragma unroll
        for (int d=0;d<4;d++){
          o[su][d] = __builtin_amdgcn_mfma_f32_16x16x32_bf16(vf[d][0], pf0, o[su][d], 0,0,0);
          o[su][d] = __builtin_amdgcn_mfma_f32_16x16x32_bf16(vf[d][1], pf1, o[su][d], 0,0,0);
        }
      }
    }
  }

  #pragma unroll
  for (int su=0; su<2; su++) {
    float lpv = lp[su];
    lpv += __shfl_xor(lpv, 16, 64);
    lpv += __shfl_xor(lpv, 32, 64);
    float rl = 1.0f / lpv;
    const int qq = qw0 + su*16 + li;
    #pragma unroll
    for (int d=0;d<4;d++){
      u16x4 wv;
      #pragma unroll
      for (int r=0;r<4;r++) wv[r] = f2b(o[su][d][r] * rl);
      *(u16x4*)&ctx[(size_t)(b*TT + qq)*DM + h*DK + d*16 + quad*4] = wv;
    }
  }
}

extern "C" void kernel_launch(void* const* d_in, const int* in_sizes, int n_in,
                              void* d_out, int out_size, void* d_ws, size_t ws_size,
                              hipStream_t stream) {
  const float* q   = (const float*)d_in[0];
  const float* k   = (const float*)d_in[1];
  const float* v   = (const float*)d_in[2];
  // d_in[3]: mask (int32 causal tril) — causality hard-coded in flash kernel
  const float* wq  = (const float*)d_in[4];
  const float* bq  = (const float*)d_in[5];
  const float* wk  = (const float*)d_in[6];
  const float* bk  = (const float*)d_in[7];
  const float* wv  = (const float*)d_in[8];
  const float* bv  = (const float*)d_in[9];
  const float* wo  = (const float*)d_in[10];
  const float* bo  = (const float*)d_in[11];
  float* out = (float*)d_out;

  const size_t SZ = (size_t)BATCH*TT*DM;
  u16* wt  = (u16*)d_ws;                        // 4 x 1024x1024 bf16 = 8 MB
  u16* qb  = wt + (size_t)4*DM*DM;
  u16* kb  = qb + SZ;
  u16* vb  = kb + SZ;
  u16* qh  = vb + SZ;
  u16* kh  = qh + SZ;
  u16* vhT = kh + SZ;
  u16* ctx = qb;                                // alias: qb dead after gemm_qkv

  prep<<<dim3(2048, 1, 7), 256, 0, stream>>>(q, k, v, wq, wk, wv, wo, qb, kb, vb, wt);

  gemm_qkv<<<dim3(192, 1, 1), 512, 0, stream>>>(qb, kb, vb, wt, bq, bk, bv, qh, kh, vhT);

  flash<<<dim3(BATCH*NH, 16), 256, 0, stream>>>(qh, kh, vhT, ctx);

  gemm_out64<<<dim3(4096/128, DM/64), 256, 0, stream>>>(ctx, wt + (size_t)3*DM*DM, bo, out);
}

// Round 12
// 216.900 us; speedup vs baseline: 1.5327x; 1.1349x over previous
//
#include <hip/hip_runtime.h>
#include <hip/hip_bf16.h>

#define DM 1024
#define NH 16
#define DK 64
#define TT 2048
#define BATCH 2

typedef __attribute__((ext_vector_type(8))) short bf16x8;
typedef __attribute__((ext_vector_type(4))) float f32x4;
typedef __attribute__((ext_vector_type(4))) unsigned short u16x4;
typedef unsigned short u16;

__device__ inline u16 f2b(float x){ __hip_bfloat16 h = __float2bfloat16(x); return *reinterpret_cast<u16*>(&h); }

__device__ inline void gl_lds16(const u16* g, u16* l) {
  __builtin_amdgcn_global_load_lds(
      (const __attribute__((address_space(1))) unsigned int*)g,
      (__attribute__((address_space(3))) unsigned int*)l, 16, 0, 0);
}

// ---------- prep: fused fp32->bf16 activation convert (z<3) + weight transpose (z>=3) ----------
__global__ __launch_bounds__(256) void prep(const float* __restrict__ q, const float* __restrict__ k,
                                            const float* __restrict__ v,
                                            const float* __restrict__ wq, const float* __restrict__ wk,
                                            const float* __restrict__ wv, const float* __restrict__ wo,
                                            u16* __restrict__ qb, u16* __restrict__ kb,
                                            u16* __restrict__ vb, u16* __restrict__ wt) {
  int z = blockIdx.z;
  if (z < 3) {
    const float* src = z==0 ? q : z==1 ? k : v;
    u16* dst = z==0 ? qb : z==1 ? kb : vb;
    size_t i = ((size_t)blockIdx.x*256 + threadIdx.x)*8;
    f32x4 a = *(const f32x4*)(src+i);
    f32x4 b = *(const f32x4*)(src+i+4);
    union { bf16x8 v8; u16 e[8]; } u;
    #pragma unroll
    for (int j=0;j<4;j++){ u.e[j] = f2b(a[j]); u.e[4+j] = f2b(b[j]); }
    *(bf16x8*)(dst+i) = u.v8;
  } else {
    int bx = blockIdx.x;
    if (bx >= 1024) return;
    __shared__ float tile[32][33];
    const float* src = z==3 ? wq : z==4 ? wk : z==5 ? wv : wo;
    u16* dst = wt + (size_t)(z-3)*DM*DM;
    int bxx = bx & 31, byy = bx >> 5;
    int tx = threadIdx.x & 31, ty = threadIdx.x >> 5;   // 32 x 8
    int x  = bxx*32 + tx;
    int y0 = byy*32 + ty;
    #pragma unroll
    for (int i=0;i<32;i+=8) tile[ty+i][tx] = src[(size_t)(y0+i)*DM + x];
    __syncthreads();
    int xo = byy*32 + tx;
    int yo = bxx*32 + ty;
    #pragma unroll
    for (int i=0;i<32;i+=8) dst[(size_t)(yo+i)*DM + xo] = f2b(tile[tx][ty+i]);
  }
}

// ---------- QKV projection GEMM, v3: 256x256 tile, 8 waves, 8-phase schedule (T3+T4),
// ---------- counted vmcnt(4) twice/iter, granule-XOR LDS swizzle (T2), setprio (T5),
// ---------- XCD-chunked block swizzle (T1).
// mode 0 (z<2): row-major bf16 out [b*t][DM]; mode 1 (z==2): V-transposed [b,h,d,t] (u16x4).
// Q out is scaled by 0.125*log2(e) so flash can use exp2 (single v_exp_f32, no mul).
__global__ __launch_bounds__(512, 2) void gemm_qkv(const u16* __restrict__ qb, const u16* __restrict__ kb,
                                                   const u16* __restrict__ vb, const u16* __restrict__ wt,
                                                   const float* __restrict__ bq, const float* __restrict__ bk,
                                                   const float* __restrict__ bv,
                                                   u16* __restrict__ qh, u16* __restrict__ kh,
                                                   u16* __restrict__ vhT) {
  // flat grid 192 = 3z * 16m * 4n, XCD-chunked swizzle (192 % 8 == 0)
  const int bid = blockIdx.x;
  const int swz = (bid & 7)*24 + (bid >> 3);
  const int z  = swz >> 6;
  const int rb = swz & 63;
  const int row0 = (rb >> 2) * 256;
  const int col0 = (rb & 3) * 256;

  const u16* A = z==0 ? qb : z==1 ? kb : vb;
  const u16* W = wt + (size_t)z*DM*DM;
  const float* bias = z==0 ? bq : z==1 ? bk : bv;
  u16* outv = z==0 ? qh : z==1 ? kh : vhT;
  const int mode = (z==2);
  const float oscale = (z==0) ? 0.18033688f : 1.0f;   // 1/sqrt(64) * log2(e)

  // 2 slots x (A: 256x64 + B: 256x64) bf16 = 128 KiB
  __shared__ __align__(16) u16 As[2][16384];
  __shared__ __align__(16) u16 Bs[2][16384];

  const int tid = threadIdx.x, lane = tid & 63, wid = tid >> 6;
  const int li = lane & 15, quad = lane >> 4, l7 = lane & 7;
  const int wr = wid >> 2, wc = wid & 3;      // 2M x 4N waves, each owns 128x64 of C

  int r_[2], gs_[2];
  #pragma unroll
  for (int c=0;c<2;c++){ int idx = tid + c*512; int rr = idx>>3; int gd = idx&7; r_[c]=rr; gs_[c]=gd^(rr&7); }

  auto stage = [&](int op, int t, int hf, int slot){   // op: 0=A, 1=B(W)
    const u16* base = op ? W : A;
    const int rowbase = (op ? col0 : row0) + hf*128;
    u16* lb = (op ? Bs[slot] : As[slot]) + hf*8192;
    #pragma unroll
    for (int c=0;c<2;c++){
      gl_lds16(base + (size_t)(rowbase + r_[c])*DM + t*64 + gs_[c]*8,
               lb + ((wid*64 + c*512) << 3));
    }
  };

  f32x4 acc[8][4];
  #pragma unroll
  for (int i=0;i<8;i++)
    #pragma unroll
    for (int j=0;j<4;j++) acc[i][j] = f32x4{0.f,0.f,0.f,0.f};

  stage(1, 0, 0, 0); stage(1, 0, 1, 0);
  stage(0, 0, 0, 0); stage(0, 0, 1, 0);
  stage(1, 1, 0, 1); stage(1, 1, 1, 1);
  asm volatile("s_waitcnt vmcnt(4)" ::: "memory");
  __builtin_amdgcn_s_barrier();

  bf16x8 b[4][2];
  for (int i = 0; i < 8; i++) {
    const int t2 = 2*i;
    #pragma unroll
    for (int half = 0; half < 2; half++) {
      const int slot = half;
      #pragma unroll
      for (int q = 0; q < 4; q++) {
        if (q == 0) {
          const u16* bb = Bs[slot] + (wc>>1)*8192 + (wc&1)*4096;
          #pragma unroll
          for (int c=0;c<4;c++)
            #pragma unroll
            for (int kh=0;kh<2;kh++)
              b[c][kh] = *(const bf16x8*)&bb[(c*16 + li)*64 + ((quad + 4*kh) ^ l7)*8];
        }
        bf16x8 a[2][2];
        {
          const u16* ab = As[slot] + wr*8192;
          #pragma unroll
          for (int rr2=0; rr2<2; rr2++)
            #pragma unroll
            for (int kh=0;kh<2;kh++)
              a[rr2][kh] = *(const bf16x8*)&ab[((q*2+rr2)*16 + li)*64 + ((quad + 4*kh) ^ l7)*8];
        }
        {
          const int sop = (q >= 2);
          const int st  = t2 + 1 + half + (q >= 2);
          const int shf = q & 1;
          const int ssl = (q >= 2) ? half : (1 - half);
          if (st <= 15) stage(sop, st, shf, ssl);
        }
        if (q == 0) asm volatile("s_waitcnt lgkmcnt(8)" ::: "memory");
        __builtin_amdgcn_s_barrier();
        asm volatile("s_waitcnt lgkmcnt(0)" ::: "memory");
        __builtin_amdgcn_sched_barrier(0);
        __builtin_amdgcn_s_setprio(1);
        #pragma unroll
        for (int rr2=0; rr2<2; rr2++)
          #pragma unroll
          for (int c=0;c<4;c++)
            #pragma unroll
            for (int kh=0;kh<2;kh++)
              acc[q*2+rr2][c] = __builtin_amdgcn_mfma_f32_16x16x32_bf16(a[rr2][kh], b[c][kh], acc[q*2+rr2][c], 0,0,0);
        __builtin_amdgcn_s_setprio(0);
        if (q == 3) {
          if (half == 0) {
            if (i < 7) asm volatile("s_waitcnt vmcnt(4)" ::: "memory");
            else       asm volatile("s_waitcnt vmcnt(0)" ::: "memory");
          } else {
            if (i < 7) asm volatile("s_waitcnt vmcnt(4)" ::: "memory");
          }
        }
        __builtin_amdgcn_s_barrier();
      }
    }
  }

  // C layout: col=lane&15, row=quad*4+reg  [m89/m91]
  if (!mode) {
    #pragma unroll
    for (int c=0;c<4;c++) {
      int col = col0 + wc*64 + c*16 + li;
      float bsv = bias[col];
      #pragma unroll
      for (int fr=0; fr<8; fr++) {
        int rowb = row0 + wr*128 + fr*16 + quad*4;
        #pragma unroll
        for (int r=0;r<4;r++)
          outv[(size_t)(rowb + r)*DM + col] = f2b((acc[fr][c][r] + bsv) * oscale);
      }
    }
  } else {
    #pragma unroll
    for (int c=0;c<4;c++) {
      int col = col0 + wc*64 + c*16 + li;
      float bsv = bias[col];
      int hh = col >> 6, d = col & 63;
      #pragma unroll
      for (int fr=0; fr<8; fr++) {
        int rowb = row0 + wr*128 + fr*16 + quad*4;
        int bb = rowb >> 11, t0 = rowb & (TT-1);
        u16x4 w;
        #pragma unroll
        for (int r=0;r<4;r++) w[r] = f2b(acc[fr][c][r] + bsv);
        *(u16x4*)&outv[(((size_t)(bb*NH + hh)*DK + d)*TT) + t0] = w;
      }
    }
  }
}

// ---------- output GEMM, v2: depth-2 pipeline + swizzle, 128x64 tiles ----------
__global__ __launch_bounds__(256) void gemm_out64(const u16* __restrict__ A, const u16* __restrict__ W,
                                                  const float* __restrict__ bias, float* __restrict__ out) {
  __shared__ __align__(16) u16 As[3][128*32];
  __shared__ __align__(16) u16 Bs[3][64*32];
  const int tid = threadIdx.x, lane = tid & 63, wid = tid >> 6;
  const int li = lane & 15, quad = lane >> 4;
  const int row0 = blockIdx.x*128, col0 = blockIdx.y*64;
  const int wr = wid & 1, wc = wid >> 1;

  const int srow = lane >> 2;
  const int scol = ((lane & 3) ^ ((srow >> 1) & 3)) * 8;
  const int rsw  = (li >> 1) & 3;

  auto stage = [&](int hh, int bufi) {
    const int kk = hh*32;
    #pragma unroll
    for (int c=0;c<2;c++) {
      int ch = wid*2 + c;
      gl_lds16(A + (size_t)(row0 + ch*16 + srow)*DM + kk + scol, &As[bufi][ch*512]);
    }
    gl_lds16(W + (size_t)(col0 + wid*16 + srow)*DM + kk + scol, &Bs[bufi][wid*512]);
  };

  f32x4 acc[4][2];
  #pragma unroll
  for (int i=0;i<4;i++)
    #pragma unroll
    for (int j=0;j<2;j++) acc[i][j] = f32x4{0.f,0.f,0.f,0.f};

  stage(0, 0);
  stage(1, 1);
  asm volatile("s_waitcnt vmcnt(3)" ::: "memory");
  __builtin_amdgcn_s_barrier();

  int buf = 0;
  for (int h = 0; h < 32; h++) {
    bf16x8 a[4], b[2];
    #pragma unroll
    for (int i=0;i<4;i++) a[i] = *(const bf16x8*)&As[buf][(wr*64 + i*16 + li)*32 + (quad ^ rsw)*8];
    #pragma unroll
    for (int j=0;j<2;j++) b[j] = *(const bf16x8*)&Bs[buf][(wc*32 + j*16 + li)*32 + (quad ^ rsw)*8];

    if (h < 30) { int nb = buf + 2; if (nb >= 3) nb -= 3; stage(h+2, nb); }

    __builtin_amdgcn_s_setprio(1);
    #pragma unroll
    for (int i=0;i<4;i++)
      #pragma unroll
      for (int j=0;j<2;j++)
        acc[i][j] = __builtin_amdgcn_mfma_f32_16x16x32_bf16(a[i], b[j], acc[i][j], 0,0,0);
    __builtin_amdgcn_s_setprio(0);

    if (h < 30)       asm volatile("s_waitcnt vmcnt(3)" ::: "memory");
    else if (h == 30) asm volatile("s_waitcnt vmcnt(0)" ::: "memory");
    __builtin_amdgcn_s_barrier();
    if (++buf == 3) buf = 0;
  }

  #pragma unroll
  for (int j=0;j<2;j++) {
    int col = col0 + wc*32 + j*16 + li;
    float bsv = bias[col];
    #pragma unroll
    for (int i=0;i<4;i++) {
      #pragma unroll
      for (int r=0;r<4;r++) {
        int row = row0 + wr*64 + i*16 + quad*4 + r;
        out[(size_t)row*DM + col] = acc[i][j][r] + bsv;
      }
    }
  }
}

// ---------- flash v12: v7's proven inner loop with 64-q blocks -> 4x the blocks.
// ---------- r11 insight: occupancy was GRID-limited (512 blocks / 256 CU = 2/CU), never
// ---------- VGPR/LDS. v12: 4 waves x 16 q, grid (32 bh, 32 qtiles) = 1024 blocks;
// ---------- LDS 40KB (2x8K K + 2x8K V dbuf + 8K Pb) -> exactly 4 blocks/CU = 16 waves/CU
// ---------- of mutually independent (de-phased) block streams. Per-CU totals uniform:
// ---------- round-robin gives qt = {31-g, 23-g, g, g+8} -> 66 chunks/CU.
// ---------- Every wave is active in every chunk of its block (qw0 >= last k0); only the
// ---------- final chunk masks. K/V staged double-buffered, granule-XOR swizzled (T2).
__global__ __launch_bounds__(256) void flash(const u16* __restrict__ qh, const u16* __restrict__ kh,
                                             const u16* __restrict__ vhT, u16* __restrict__ ctx) {
  const int bh = blockIdx.x;                   // 0..31
  const int y  = blockIdx.y;                   // 0..31
  const int qt = (y < 16) ? (31 - y) : (y - 16);  // complementary totals pairing
  const int b = bh >> 4, h = bh & 15;
  const u16* Q  = qh  + (size_t)b*TT*DM + h*DK;
  const u16* K  = kh  + (size_t)b*TT*DM + h*DK;
  const u16* Vt = vhT + (size_t)bh*DK*TT;      // [d][t]

  const int tid = threadIdx.x, lane = tid & 63, wid = tid >> 6;
  const int li = lane & 15, quad = lane >> 4, l7 = lane & 7;

  // granule-XOR swizzled rows (stride 64 u16): slot = g ^ (row&7) -> 0-conflict b128
  __shared__ __align__(16) u16 Kl[2][4096];
  __shared__ __align__(16) u16 Vl[2][4096];
  __shared__ __align__(16) u16 Pb[4][16][64];

  const int sr = tid >> 3;                     // 0..31
  const int sg = tid & 7;                      // granule 0..7
  const int ssl = (sg ^ (sr & 7)) * 8;         // swizzled slot; (sr+32)&7 == sr&7

  const int nt  = qt + 1;                      // 64-key chunks for this block
  const int qw0 = qt*64 + wid*16;              // wave q base (16 q per wave)

  bf16x8 qf0 = *(const bf16x8*)&Q[(size_t)(qw0 + li)*DM +      quad*8];
  bf16x8 qf1 = *(const bf16x8*)&Q[(size_t)(qw0 + li)*DM + 32 + quad*8];

  f32x4 o[4];
  #pragma unroll
  for (int d=0; d<4; d++) o[d] = f32x4{0.f,0.f,0.f,0.f};
  float lp = 0.f;

  // prologue: chunk 0 -> regs
  bf16x8 kr0 = *(const bf16x8*)&K[(size_t)(sr   )*DM + sg*8];
  bf16x8 kr1 = *(const bf16x8*)&K[(size_t)(sr+32)*DM + sg*8];
  bf16x8 vr0 = *(const bf16x8*)&Vt[(size_t)(sr   )*TT + sg*8];
  bf16x8 vr1 = *(const bf16x8*)&Vt[(size_t)(sr+32)*TT + sg*8];

  for (int n = 0; n < nt; n++) {
    const int k0 = n*64;
    const int s = n & 1;
    *(bf16x8*)&Kl[s][(sr   )*64 + ssl] = kr0;
    *(bf16x8*)&Kl[s][(sr+32)*64 + ssl] = kr1;
    *(bf16x8*)&Vl[s][(sr   )*64 + ssl] = vr0;
    *(bf16x8*)&Vl[s][(sr+32)*64 + ssl] = vr1;
    __syncthreads();
    if (n+1 < nt) {
      const int k1 = k0 + 64;
      kr0 = *(const bf16x8*)&K[(size_t)(k1+sr   )*DM + sg*8];
      kr1 = *(const bf16x8*)&K[(size_t)(k1+sr+32)*DM + sg*8];
      vr0 = *(const bf16x8*)&Vt[(size_t)(sr   )*TT + k1 + sg*8];
      vr1 = *(const bf16x8*)&Vt[(size_t)(sr+32)*TT + k1 + sg*8];
    }

    // ---- QK: S^T = K @ Q^T ----
    f32x4 sacc[4];
    __builtin_amdgcn_s_setprio(1);
    #pragma unroll
    for (int c=0;c<4;c++) {
      bf16x8 kf0 = *(const bf16x8*)&Kl[s][(c*16+li)*64 + ((quad    ) ^ l7)*8];
      bf16x8 kf1 = *(const bf16x8*)&Kl[s][(c*16+li)*64 + ((quad + 4) ^ l7)*8];
      f32x4 t = __builtin_amdgcn_mfma_f32_16x16x32_bf16(kf0, qf0, f32x4{0.f,0.f,0.f,0.f}, 0,0,0);
      sacc[c] = __builtin_amdgcn_mfma_f32_16x16x32_bf16(kf1, qf1, t, 0,0,0);
    }
    __builtin_amdgcn_s_setprio(0);

    // ---- softmax -> Pb roundtrip -> pf ----
    const int qq = qw0 + li;
    float p[4][4];
    if (n == nt-1) {                           // diagonal chunk: mask
      #pragma unroll
      for (int c=0;c<4;c++)
        #pragma unroll
        for (int r=0;r<4;r++){
          int key = k0 + c*16 + quad*4 + r;
          p[c][r] = (key <= qq) ? exp2f(sacc[c][r]) : 0.f;
        }
    } else {
      #pragma unroll
      for (int c=0;c<4;c++)
        #pragma unroll
        for (int r=0;r<4;r++)
          p[c][r] = exp2f(sacc[c][r]);
    }
    #pragma unroll
    for (int c=0;c<4;c++)
      #pragma unroll
      for (int r=0;r<4;r++)
        lp += p[c][r];

    #pragma unroll
    for (int c=0;c<4;c++) {
      u16x4 wv;
      #pragma unroll
      for (int r=0;r<4;r++) wv[r] = f2b(p[c][r]);
      const int gc = c*2 + (quad>>1);
      *(u16x4*)&Pb[wid][li][((gc ^ l7)*8) + (quad&1)*4] = wv;
    }
    __builtin_amdgcn_wave_barrier();
    __asm__ __volatile__("s_waitcnt lgkmcnt(0)");
    bf16x8 pf0 = *(const bf16x8*)&Pb[wid][li][((quad    ) ^ l7)*8];
    bf16x8 pf1 = *(const bf16x8*)&Pb[wid][li][((quad + 4) ^ l7)*8];

    // ---- PV ----
    __builtin_amdgcn_s_setprio(1);
    #pragma unroll
    for (int d=0;d<4;d++){
      bf16x8 vf0 = *(const bf16x8*)&Vl[s][(d*16+li)*64 + ((quad    ) ^ l7)*8];
      bf16x8 vf1 = *(const bf16x8*)&Vl[s][(d*16+li)*64 + ((quad + 4) ^ l7)*8];
      o[d] = __builtin_amdgcn_mfma_f32_16x16x32_bf16(vf0, pf0, o[d], 0,0,0);
      o[d] = __builtin_amdgcn_mfma_f32_16x16x32_bf16(vf1, pf1, o[d], 0,0,0);
    }
    __builtin_amdgcn_s_setprio(0);
  }

  lp += __shfl_xor(lp, 16, 64);
  lp += __shfl_xor(lp, 32, 64);
  float rl = 1.0f / lp;
  const int qq = qw0 + li;
  #pragma unroll
  for (int d=0;d<4;d++){
    u16x4 wv;
    #pragma unroll
    for (int r=0;r<4;r++) wv[r] = f2b(o[d][r] * rl);
    *(u16x4*)&ctx[(size_t)(b*TT + qq)*DM + h*DK + d*16 + quad*4] = wv;
  }
}

extern "C" void kernel_launch(void* const* d_in, const int* in_sizes, int n_in,
                              void* d_out, int out_size, void* d_ws, size_t ws_size,
                              hipStream_t stream) {
  const float* q   = (const float*)d_in[0];
  const float* k   = (const float*)d_in[1];
  const float* v   = (const float*)d_in[2];
  // d_in[3]: mask (int32 causal tril) — causality hard-coded in flash kernel
  const float* wq  = (const float*)d_in[4];
  const float* bq  = (const float*)d_in[5];
  const float* wk  = (const float*)d_in[6];
  const float* bk  = (const float*)d_in[7];
  const float* wv  = (const float*)d_in[8];
  const float* bv  = (const float*)d_in[9];
  const float* wo  = (const float*)d_in[10];
  const float* bo  = (const float*)d_in[11];
  float* out = (float*)d_out;

  const size_t SZ = (size_t)BATCH*TT*DM;
  u16* wt  = (u16*)d_ws;                        // 4 x 1024x1024 bf16 = 8 MB
  u16* qb  = wt + (size_t)4*DM*DM;
  u16* kb  = qb + SZ;
  u16* vb  = kb + SZ;
  u16* qh  = vb + SZ;
  u16* kh  = qh + SZ;
  u16* vhT = kh + SZ;
  u16* ctx = qb;                                // alias: qb dead after gemm_qkv

  prep<<<dim3(2048, 1, 7), 256, 0, stream>>>(q, k, v, wq, wk, wv, wo, qb, kb, vb, wt);

  gemm_qkv<<<dim3(192, 1, 1), 512, 0, stream>>>(qb, kb, vb, wt, bq, bk, bv, qh, kh, vhT);

  flash<<<dim3(BATCH*NH, 32), 256, 0, stream>>>(qh, kh, vhT, ctx);

  gemm_out64<<<dim3(4096/128, DM/64), 256, 0, stream>>>(ctx, wt + (size_t)3*DM*DM, bo, out);
}